// Round 1
// baseline (811.981 us; speedup 1.0000x reference)
//
#include <hip/hip_runtime.h>

// AlignmentLossWithSinkhorn on MI355X.
// Factored Sinkhorn: Q = diag(u) E diag(v), E = exp(A B^T / eps) recomputed
// on the fly via bf16 MFMA (A,B are 4MB total -> L2-resident). 40 GEMV-like
// passes + one fused final (C = E^T (u.B), loss) pass. No 256MB matrix.

#define NN 8192
#define DD 64
#define NITER 20
#define NSPLIT 8

typedef __attribute__((ext_vector_type(8))) short bf16x8;
typedef __attribute__((ext_vector_type(4))) float f32x4;

__device__ __forceinline__ float fexp2(float x){
#if __has_builtin(__builtin_amdgcn_exp2f)
  return __builtin_amdgcn_exp2f(x);
#else
  float r; asm("v_exp_f32 %0, %1" : "=v"(r) : "v"(x)); return r;
#endif
}

__device__ __forceinline__ unsigned short f2bf(float f){
  unsigned u = __float_as_uint(f);
  u = u + 0x7FFFu + ((u >> 16) & 1u);   // RNE
  return (unsigned short)(u >> 16);
}

// ---- prep: bf16 copies (A scaled by log2e/eps) + B^T (d-major) -------------
__global__ void k_prep(const float* __restrict__ A, const float* __restrict__ B,
                       unsigned short* __restrict__ Abf,
                       unsigned short* __restrict__ Bbf,
                       unsigned short* __restrict__ Bt){
  int i = blockIdx.x * 256 + threadIdx.x;      // over N*D
  const float SCL = 1.4426950408889634f / 0.05f;  // log2(e)/EPSILON
  float a = A[i], b = B[i];
  Abf[i] = f2bf(a * SCL);
  unsigned short bb = f2bf(b);
  Bbf[i] = bb;
  Bt[(i & (DD - 1)) * NN + (i >> 6)] = bb;
}

// ---- one Sinkhorn half-iteration -------------------------------------------
// out[s][p] = sum_{q in split s} exp2(X[p].Y[q]) * w(q),
// w(q) = 1 (mode 0)  or  1/(8192 * sum_s inParts[s][q]) (mode 1).
// grid (128 row-tiles, 8 Y-splits), block 256 (4 waves x 16 rows).
__global__ __launch_bounds__(256) void k_pass(
    const unsigned short* __restrict__ Xbf,
    const unsigned short* __restrict__ Ybf,
    const float* __restrict__ inParts,
    float* __restrict__ outParts,
    int mode){
  __shared__ alignas(16) char yl[256 * 128];   // 256 Y-rows, XOR-swizzled bf16
  __shared__ float wl[256];
  const int t = threadIdx.x;
  const int wave = t >> 6, lane = t & 63;
  const int l15 = lane & 15, g = lane >> 4;
  const int rowBase = blockIdx.x * 64 + wave * 16;
  const int yBase0 = blockIdx.y * 1024;

  // owned-row A-fragments (M = l15, k = g*8+e ; kstep1 at +32)
  const bf16x8* xp = (const bf16x8*)(Xbf + (rowBase + l15) * 64 + g * 8);
  bf16x8 af0 = xp[0];
  bf16x8 af1 = xp[4];

  float yp0 = 0.f, yp1 = 0.f, yp2 = 0.f, yp3 = 0.f;
  const f32x4 z4 = {0.f, 0.f, 0.f, 0.f};

  for(int st = 0; st < 4; ++st){
    const int yBase = yBase0 + st * 256;
    // stage 256 Y-rows (32KB), coalesced 16B chunks, swizzled LDS dst
    const uint4* src = (const uint4*)(Ybf + (size_t)yBase * 64);
    #pragma unroll
    for(int s = 0; s < 8; ++s){
      int ci = s * 256 + t;
      uint4 v = src[ci];
      int row = ci >> 3, c = ci & 7;
      *(uint4*)(yl + row * 128 + ((c * 16) ^ ((row & 7) << 4))) = v;
    }
    { // stage weights (fused transform of previous pass's split-partials)
      int q = yBase + t;
      float w = 1.0f;
      if(mode){
        float ssum = 0.f;
        #pragma unroll
        for(int s = 0; s < NSPLIT; ++s) ssum += inParts[s * NN + q];
        w = 1.0f / (8192.0f * ssum);
      }
      wl[t] = w;
    }
    __syncthreads();
    #pragma unroll
    for(int ct = 0; ct < 16; ++ct){
      int q = ct * 16 + l15;
      int sw = (q & 7) << 4;
      bf16x8 b0 = *(const bf16x8*)(yl + q * 128 + ((g * 16) ^ sw));
      bf16x8 b1 = *(const bf16x8*)(yl + q * 128 + ((64 + g * 16) ^ sw));
      f32x4 acc = __builtin_amdgcn_mfma_f32_16x16x32_bf16(af0, b0, z4, 0, 0, 0);
      acc = __builtin_amdgcn_mfma_f32_16x16x32_bf16(af1, b1, acc, 0, 0, 0);
      float wq = wl[ct * 16 + l15];
      yp0 += fexp2(acc[0]) * wq;
      yp1 += fexp2(acc[1]) * wq;
      yp2 += fexp2(acc[2]) * wq;
      yp3 += fexp2(acc[3]) * wq;
    }
    __syncthreads();
  }
  // reduce over the 16 columns held across lanes of each group
  #pragma unroll
  for(int m = 1; m < 16; m <<= 1){
    yp0 += __shfl_xor(yp0, m, 64);
    yp1 += __shfl_xor(yp1, m, 64);
    yp2 += __shfl_xor(yp2, m, 64);
    yp3 += __shfl_xor(yp3, m, 64);
  }
  if(l15 == 0){
    float* o = outParts + blockIdx.y * NN + rowBase + g * 4;
    o[0] = yp0; o[1] = yp1; o[2] = yp2; o[3] = yp3;
  }
}

// ---- u/z finalize ----------------------------------------------------------
__global__ void k_uz(const float* __restrict__ yparts, const float* __restrict__ zparts,
                     float* __restrict__ u, float* __restrict__ z){
  int i = blockIdx.x * 256 + threadIdx.x;   // 16384 threads
  if(i < NN){
    float s = 0.f;
    #pragma unroll
    for(int k = 0; k < NSPLIT; ++k) s += yparts[k * NN + i];
    u[i] = 1.0f / (8192.0f * s);
  } else {
    int j = i - NN;
    float s = 0.f;
    #pragma unroll
    for(int k = 0; k < NSPLIT; ++k) s += zparts[k * NN + j];
    z[j] = s;
  }
}

// ---- final: C = E^T (u.B) via flash-style double MFMA, then loss -----------
// block = 128 thr (2 waves x 16 n-rows), grid 256. aligned_n = C_n / z_n.
__global__ __launch_bounds__(128) void k_final(
    const unsigned short* __restrict__ Abf,
    const unsigned short* __restrict__ Bbf,
    const unsigned short* __restrict__ Bt,
    const float* __restrict__ u,
    const float* __restrict__ zv,
    const float* __restrict__ Afp,
    float* __restrict__ lossParts){
  const int t = threadIdx.x, wave = t >> 6, lane = t & 63;
  const int l15 = lane & 15, g = lane >> 4;
  const int nb = blockIdx.x * 32 + wave * 16;

  const bf16x8* ap = (const bf16x8*)(Abf + (nb + l15) * 64 + g * 8);
  bf16x8 nf0 = ap[0], nf1 = ap[4];

  f32x4 c0 = {0,0,0,0}, c1 = {0,0,0,0}, c2 = {0,0,0,0}, c3 = {0,0,0,0};
  const f32x4 z4 = {0,0,0,0};
  const int lA = l15 + (((g << 1) & 3) << 4);     // source lane for P-transpose
  const bool hi = lane >= 32;

  for(int mb = 0; mb < NN; mb += 32){
    unsigned pA0 = 0, pA1 = 0, pB0 = 0, pB1 = 0;
    #pragma unroll
    for(int half = 0; half < 2; ++half){
      int m16 = mb + half * 16;
      const bf16x8* mp = (const bf16x8*)(Bbf + (m16 + l15) * 64 + g * 8);
      bf16x8 m0 = mp[0], m1 = mp[4];
      // S'[m][n] = (log2e/eps) * b_m . a_n   (M-rows = m, N-cols = n)
      f32x4 s = __builtin_amdgcn_mfma_f32_16x16x32_bf16(m0, nf0, z4, 0, 0, 0);
      s = __builtin_amdgcn_mfma_f32_16x16x32_bf16(m1, nf1, s, 0, 0, 0);
      float4 u4 = *(const float4*)(u + m16 + g * 4);
      float e0 = fexp2(s[0]) * u4.x;
      float e1 = fexp2(s[1]) * u4.y;
      float e2 = fexp2(s[2]) * u4.z;
      float e3 = fexp2(s[3]) * u4.w;
      unsigned w0 = (unsigned)f2bf(e0) | ((unsigned)f2bf(e1) << 16);
      unsigned w1 = (unsigned)f2bf(e2) | ((unsigned)f2bf(e3) << 16);
      if(half == 0){ pA0 = w0; pA1 = w1; } else { pB0 = w0; pB1 = w1; }
    }
    // cross-lane transpose: build P' A-fragment (n = l15, k = m = 8g+e)
    unsigned sA0a = (unsigned)__shfl((int)pA0, lA, 64);
    unsigned sA1a = (unsigned)__shfl((int)pA1, lA, 64);
    unsigned sA0b = (unsigned)__shfl((int)pA0, lA + 16, 64);
    unsigned sA1b = (unsigned)__shfl((int)pA1, lA + 16, 64);
    unsigned sB0a = (unsigned)__shfl((int)pB0, lA, 64);
    unsigned sB1a = (unsigned)__shfl((int)pB1, lA, 64);
    unsigned sB0b = (unsigned)__shfl((int)pB0, lA + 16, 64);
    unsigned sB1b = (unsigned)__shfl((int)pB1, lA + 16, 64);
    union { unsigned u32[4]; bf16x8 v; } pk;
    pk.u32[0] = hi ? sB0a : sA0a;
    pk.u32[1] = hi ? sB1a : sA1a;
    pk.u32[2] = hi ? sB0b : sA0b;
    pk.u32[3] = hi ? sB1b : sA1b;
    // PV: C[n][d] += P'[n][m] * B[m][d], B-op fragments from pre-transposed Bt
    {
      const bf16x8* bp0 = (const bf16x8*)(Bt + (size_t)(0 * 16 + l15) * NN + mb + g * 8);
      const bf16x8* bp1 = (const bf16x8*)(Bt + (size_t)(1 * 16 + l15) * NN + mb + g * 8);
      const bf16x8* bp2 = (const bf16x8*)(Bt + (size_t)(2 * 16 + l15) * NN + mb + g * 8);
      const bf16x8* bp3 = (const bf16x8*)(Bt + (size_t)(3 * 16 + l15) * NN + mb + g * 8);
      c0 = __builtin_amdgcn_mfma_f32_16x16x32_bf16(pk.v, bp0[0], c0, 0, 0, 0);
      c1 = __builtin_amdgcn_mfma_f32_16x16x32_bf16(pk.v, bp1[0], c1, 0, 0, 0);
      c2 = __builtin_amdgcn_mfma_f32_16x16x32_bf16(pk.v, bp2[0], c2, 0, 0, 0);
      c3 = __builtin_amdgcn_mfma_f32_16x16x32_bf16(pk.v, bp3[0], c3, 0, 0, 0);
    }
  }
  // loss: rows n = nb + g*4 + r, cols d = dt*16 + l15
  float4 zq = *(const float4*)(zv + nb + g * 4);
  float rz0 = 1.0f / zq.x, rz1 = 1.0f / zq.y, rz2 = 1.0f / zq.z, rz3 = 1.0f / zq.w;
  float ls = 0.f;
  #pragma unroll
  for(int dt = 0; dt < 4; ++dt){
    f32x4 cc = dt == 0 ? c0 : dt == 1 ? c1 : dt == 2 ? c2 : c3;
    const float rz[4] = {rz0, rz1, rz2, rz3};
    #pragma unroll
    for(int r = 0; r < 4; ++r){
      float al = cc[r] * rz[r];
      float a = Afp[(size_t)(nb + g * 4 + r) * 64 + dt * 16 + l15];
      float df = al - a;
      ls += df * df;
    }
  }
  #pragma unroll
  for(int m = 1; m < 64; m <<= 1) ls += __shfl_xor(ls, m, 64);
  __shared__ float red[2];
  if(lane == 0) red[wave] = ls;
  __syncthreads();
  if(t == 0) lossParts[blockIdx.x] = red[0] + red[1];
}

// ---- finish: sum 256 block partials, mean ----------------------------------
__global__ void k_loss(const float* __restrict__ lossParts, float* __restrict__ out){
  int lane = threadIdx.x;   // 64
  float s = lossParts[lane] + lossParts[lane + 64] +
            lossParts[lane + 128] + lossParts[lane + 192];
  #pragma unroll
  for(int m = 1; m < 64; m <<= 1) s += __shfl_xor(s, m, 64);
  if(lane == 0) out[0] = s * (1.0f / (8192.0f * 64.0f));
}

extern "C" void kernel_launch(void* const* d_in, const int* in_sizes, int n_in,
                              void* d_out, int out_size, void* d_ws, size_t ws_size,
                              hipStream_t stream){
  const float* A = (const float*)d_in[0];   // cl_seq2intents [8192,64]
  const float* B = (const float*)d_in[1];   // seq2intents    [8192,64]
  char* ws = (char*)d_ws;
  unsigned short* Abf = (unsigned short*)(ws);                     // 1 MB
  unsigned short* Bbf = (unsigned short*)(ws + (1 << 20));         // 1 MB
  unsigned short* Bt  = (unsigned short*)(ws + (2 << 20));         // 1 MB
  float* yparts = (float*)(ws + (3 << 20));                        // 256 KB
  float* zparts = (float*)(ws + (3 << 20) + (256 << 10));          // 256 KB
  float* u      = (float*)(ws + (3 << 20) + (512 << 10));          // 32 KB
  float* z      = (float*)(ws + (3 << 20) + (544 << 10));          // 32 KB
  float* lossParts = (float*)(ws + (3 << 20) + (576 << 10));       // 1 KB

  k_prep<<<dim3((NN * DD) / 256), dim3(256), 0, stream>>>(A, B, Abf, Bbf, Bt);
  for(int it = 0; it < NITER; ++it){
    // row normalize: u = 1/(K * E v)   (E rows indexed by B-rows)
    k_pass<<<dim3(128, NSPLIT), dim3(256), 0, stream>>>(Bbf, Abf, zparts, yparts, it == 0 ? 0 : 1);
    // col normalize: v = 1/(B * E^T u)
    k_pass<<<dim3(128, NSPLIT), dim3(256), 0, stream>>>(Abf, Bbf, yparts, zparts, 1);
  }
  k_uz<<<dim3(64), dim3(256), 0, stream>>>(yparts, zparts, u, z);
  k_final<<<dim3(256), dim3(128), 0, stream>>>(Abf, Bbf, Bt, u, z, A, lossParts);
  k_loss<<<dim3(1), dim3(64), 0, stream>>>(lossParts, (float*)d_out);
}